// Round 1
// baseline (180.348 us; speedup 1.0000x reference)
//
#include <hip/hip_runtime.h>
#include <hip/hip_bf16.h>

typedef __attribute__((ext_vector_type(4))) float f32x4;
typedef __attribute__((ext_vector_type(8))) short bf16x8;

// global -> LDS direct DMA, 16 B/lane. LDS dest = wave-uniform base + lane*16.
#define GLDS16(gp, lp) __builtin_amdgcn_global_load_lds( \
    (__attribute__((address_space(1))) void*)(void*)(gp), \
    (__attribute__((address_space(3))) void*)(lp), 16, 0, 0)

static constexpr int Mtot = 49152;   // 4*24*512 rows (b,h,n)
static constexpr int Otot = 512;
static constexpr int Hh   = 24;
// K order (FEATURE-major): k = f*128 + i.  f: 0=silu, 1..5=rbf(g=f-1).
// i: 0..119 = x channels, 120..127 = t_emb.  12 K-iters of BK=64
// (8 chunks of 8 k).  Chunk-major LDS [chunk][row]x16B: ds_read_b128 and
// ds_write_b128 both land on the structural 8-lane/bank minimum -> no swizzle.

__device__ inline unsigned short f2bf(float f) {
    __hip_bfloat16 h = __float2bfloat16(f);
    unsigned short u;
    __builtin_memcpy(&u, &h, 2);
    return u;
}

// 8 values of one feature type -> 4 packed bf16x2 words (one 16B LDS chunk).
__device__ inline uint4 gen8(const int f, const float4 a, const float4 b) {
    float v[8] = {a.x, a.y, a.z, a.w, b.x, b.y, b.z, b.w};
    unsigned short s[8];
    if (f == 0) {
        #pragma unroll
        for (int e = 0; e < 8; ++e)
            s[e] = f2bf(v[e] * __builtin_amdgcn_rcpf(1.0f + __expf(-v[e])));
    } else {
        const float cg = -1.0f + 0.5f * (float)(f - 1);   // grid point
        #pragma unroll
        for (int e = 0; e < 8; ++e) {
            const float d = 2.0f * (v[e] - cg);           // inv_h = 2
            s[e] = f2bf(__expf(-d * d));
        }
    }
    uint4 u;
    u.x = s[0] | ((unsigned)s[1] << 16);
    u.y = s[2] | ((unsigned)s[3] << 16);
    u.z = s[4] | ((unsigned)s[5] << 16);
    u.w = s[6] | ((unsigned)s[7] << 16);
    return u;
}

// Wt image: linear k-major, [C=0..95][col=0..511] x 16B;
// the 16B at (C,col) holds bf16 W[k = C*8+e][col], e = 0..7.
__global__ __launch_bounds__(256) void prep_W(
        const float* __restrict__ bw, const float* __restrict__ sw,
        uint4* __restrict__ Wt)
{
    const int tid = blockIdx.x * 256 + threadIdx.x;   // = C*512 + col; 49152 total
    const int col = tid & 511;
    const int C   = tid >> 9;
    const int f   = C >> 4;
    const int i0  = (C & 15) * 8;
    unsigned short s[8];
    if (f == 0) {
        const float4 a = *(const float4*)(bw + col * 128 + i0);
        const float4 b = *(const float4*)(bw + col * 128 + i0 + 4);
        const float v[8] = {a.x, a.y, a.z, a.w, b.x, b.y, b.z, b.w};
        #pragma unroll
        for (int e = 0; e < 8; ++e) s[e] = f2bf(v[e]);
    } else {
        #pragma unroll
        for (int e = 0; e < 8; ++e)
            s[e] = f2bf(sw[(col * 128 + i0 + e) * 5 + (f - 1)]);
    }
    uint4 u;
    u.x = s[0] | ((unsigned)s[1] << 16);
    u.y = s[2] | ((unsigned)s[3] << 16);
    u.z = s[4] | ((unsigned)s[5] << 16);
    u.w = s[6] | ((unsigned)s[7] << 16);
    Wt[tid] = u;
}

// Fused KAN GEMM, full output width per block:
// block = 128 rows x 512 cols, 512 threads, 8 waves (2x4), wave tile 64x128.
// A features generated ONCE per row (no n-split redundancy). B double-buffered
// (GLDS issued one iter ahead, hides under MFMA). x cached in 32 VGPRs.
__global__ __launch_bounds__(512, 2) void gemm_kan(
        const float* __restrict__ x, const int* __restrict__ t_idx,
        const float* __restrict__ temb,
        const char* __restrict__ Wt,
        const float* __restrict__ bias,
        float* __restrict__ out)
{
    __shared__ char Alds[8 * 128 * 16];       // 16 KB, single buffer
    __shared__ char Blds[2][8 * 512 * 16];    // 2 x 64 KB double buffer

    const int t    = threadIdx.x;
    const int wave = t >> 6;
    const int lane = t & 63;
    const int ll   = lane & 15;
    const int q4   = lane >> 4;
    const int wm   = (wave >> 2) * 64;        // 0 / 64
    const int wn   = (wave & 3) * 128;        // 0..384
    const int m_base = blockIdx.x * 128;

    // ---- A-gen mapping: thread = (row, chunk-pair) ----
    const int row = t >> 2;                   // 0..127
    const int cp  = t & 3;                    // chunks cp and cp+4 each iter
    const int ht  = t_idx[(m_base >> 9) % Hh];
    const float* xrow = x + (size_t)(m_base + row) * 120;
    const float* trow = temb + ht * 8;

    // x register cache: group g = (j<<1)|h needs channels i0 = (h*8+cp+4j)*8
    float4 xc[4][2];
    #pragma unroll
    for (int g = 0; g < 4; ++g) {
        const int i0 = ((g & 1) * 8 + cp + (g >> 1) * 4) * 8;   // 8cp..120
        const float* p = (i0 < 120) ? (xrow + i0) : (trow + (i0 - 120));
        xc[g][0] = *(const float4*)p;
        xc[g][1] = *(const float4*)(p + 4);
    }

    f32x4 acc[4][8] = {};

    // B staging: wave w owns chunk w; 8 GLDS of 64 cols each.
    auto stageB = [&](int it, int buf) {
        const char* src = Wt + ((size_t)((it * 8 + wave) * 512 + lane) << 4);
        char* dst = &Blds[buf][wave * 8192];
        #pragma unroll
        for (int q = 0; q < 8; ++q)
            GLDS16(src + (q << 10), dst + (q << 10));
    };

    // ---- prologue: B(0) in flight, A(0) written, A(1) pending in regs ----
    stageB(0, 0);
    {
        uint4 a0 = gen8(0, xc[0][0], xc[0][1]);   // silu, half 0, chunk cp
        uint4 a1 = gen8(0, xc[2][0], xc[2][1]);   //                chunk cp+4
        *(uint4*)(Alds + (((cp    ) * 128 + row) << 4)) = a0;
        *(uint4*)(Alds + (((cp + 4) * 128 + row) << 4)) = a1;
    }
    uint4 p0 = gen8(0, xc[1][0], xc[1][1]);       // A(1): silu, half 1
    uint4 p1 = gen8(0, xc[3][0], xc[3][1]);
    __syncthreads();                              // drains GLDS B0 + A0 writes

    #pragma unroll
    for (int it = 0; it < 12; ++it) {
        if (it + 1 < 12) stageB(it + 1, (it + 1) & 1);   // flies across barriers

        // prep A(it+2) in regs (overlaps MFMA on the VALU pipe)
        uint4 n0 = {}, n1 = {};
        if (it + 2 < 12) {
            const int f = (it + 2) >> 1, h = (it + 2) & 1;   // f >= 1 here
            n0 = gen8(f, xc[h][0],     xc[h][1]);
            n1 = gen8(f, xc[2 + h][0], xc[2 + h][1]);
        }

        // ---- MFMA(it): A in Alds, B in Blds[it&1] ----
        const char* B = Blds[it & 1];
        #pragma unroll
        for (int kk = 0; kk < 2; ++kk) {
            const int ch = kk * 4 + q4;                      // chunk 0..7
            bf16x8 af[4], bf[8];
            #pragma unroll
            for (int mi = 0; mi < 4; ++mi)
                af[mi] = *(const bf16x8*)(Alds + ((ch * 128 + wm + mi * 16 + ll) << 4));
            #pragma unroll
            for (int ni = 0; ni < 8; ++ni)
                bf[ni] = *(const bf16x8*)(B + ((ch * 512 + wn + ni * 16 + ll) << 4));
            #pragma unroll
            for (int mi = 0; mi < 4; ++mi)
                #pragma unroll
                for (int ni = 0; ni < 8; ++ni)
                    acc[mi][ni] = __builtin_amdgcn_mfma_f32_16x16x32_bf16(
                        af[mi], bf[ni], acc[mi][ni], 0, 0, 0);
        }
        __syncthreads();                    // all waves done reading A(it)
        if (it + 1 < 12) {
            *(uint4*)(Alds + (((cp    ) * 128 + row) << 4)) = p0;   // A(it+1)
            *(uint4*)(Alds + (((cp + 4) * 128 + row) << 4)) = p1;
            p0 = n0; p1 = n1;
        }
        __syncthreads();                    // A(it+1) visible; B(it+1) drained (vmcnt0)
    }

    // C/D layout: col = lane&15, row = (lane>>4)*4 + reg  [m89-verified]
    const int col0 = wn + ll;
    const int row0 = m_base + wm + q4 * 4;
    #pragma unroll
    for (int ni = 0; ni < 8; ++ni) {
        const int col = col0 + ni * 16;
        const float bv = bias[col];
        #pragma unroll
        for (int mi = 0; mi < 4; ++mi) {
            #pragma unroll
            for (int r = 0; r < 4; ++r) {
                out[(size_t)(row0 + mi * 16 + r) * Otot + col] = acc[mi][ni][r] + bv;
            }
        }
    }
}

extern "C" void kernel_launch(void* const* d_in, const int* in_sizes, int n_in,
                              void* d_out, int out_size, void* d_ws, size_t ws_size,
                              hipStream_t stream) {
    const float* x    = (const float*)d_in[0];
    const int*   tidx = (const int*)  d_in[1];
    const float* temb = (const float*)d_in[2];
    const float* bw   = (const float*)d_in[3];
    const float* bb   = (const float*)d_in[4];
    const float* sw   = (const float*)d_in[5];
    float* out = (float*)d_out;

    char* Wt = (char*)d_ws;   // 96*512*16 = 768 KiB linear k-major image

    prep_W<<<49152 / 256, 256, 0, stream>>>(bw, sw, (uint4*)Wt);
    gemm_kan<<<Mtot / 128, 512, 0, stream>>>(x, tidx, temb, Wt, bb, out);
}